// Round 1
// 304.060 us; speedup vs baseline: 1.0564x; 1.0564x over previous
//
#include <hip/hip_runtime.h>

// MHSA. Inputs fp32, output fp32. B=4, T=2048, D=1024, H=16, hd=64.
// R8: attn softmax fully in-register (T12): swapped QK^T (mfma(K,Q) -> S^T,
// lane owns a P-row), v_cvt_pk_bf16_f32 + v_permlane32_swap_b32 build PV
// A-frags directly. Removes the P LDS round-trip (32 ds_write_u16 +
// 4 ds_read_b128 + 32 f2b per lane per kt) and the 16-wide lsum butterfly.

typedef __attribute__((ext_vector_type(8))) short bf16x8;
typedef __attribute__((ext_vector_type(8))) unsigned short u16x8;
typedef __attribute__((ext_vector_type(4))) float f32x4;
typedef __attribute__((ext_vector_type(16))) float f32x16;

#define DEV static __device__ __forceinline__

DEV unsigned short f2b(float f) {  // RTNE f32 -> bf16
  union { float f; unsigned int i; } v; v.f = f;
  unsigned int x = v.i;
  return (unsigned short)((x + 0x7FFFu + ((x >> 16) & 1u)) >> 16);
}

DEV f32x4 mfma16(bf16x8 a, bf16x8 b, f32x4 c) {
  return __builtin_amdgcn_mfma_f32_16x16x32_bf16(a, b, c, 0, 0, 0);
}
DEV f32x16 mfma32(bf16x8 a, bf16x8 b, f32x16 c) {
  return __builtin_amdgcn_mfma_f32_32x32x16_bf16(a, b, c, 0, 0, 0);
}

DEV void gl_lds16(const unsigned short* g, unsigned short* l) {
  __builtin_amdgcn_global_load_lds(
      (const __attribute__((address_space(1))) unsigned int*)g,
      (__attribute__((address_space(3))) unsigned int*)l, 16, 0, 0);
}

// cvt two f32 pairs to packed bf16, then swap upper-half(a) <-> lower-half(b)
// across the wave. Yields two A-frag words (see layout notes in attn).
DEV void pk_swap(float a0, float a1, float b0, float b1,
                 unsigned int& w_lo, unsigned int& w_hi) {
  unsigned int a, b;
  asm("v_cvt_pk_bf16_f32 %0, %1, %2" : "=v"(a) : "v"(a0), "v"(a1));
  asm("v_cvt_pk_bf16_f32 %0, %1, %2" : "=v"(b) : "v"(b0), "v"(b1));
  asm("v_permlane32_swap_b32 %0, %1" : "+v"(a), "+v"(b));
  w_lo = a; w_hi = b;
}

// ---------------------------------------------------------------- convert
__global__ __launch_bounds__(256) void f32_to_bf16(
    const float* __restrict__ in, unsigned short* __restrict__ out, int n4) {
  const int i = (blockIdx.x * 256 + threadIdx.x) * 4;
  if (i >= n4 * 4) return;
  const float4 v = *(const float4*)(in + i);
  ushort4 o;
  o.x = f2b(v.x); o.y = f2b(v.y); o.z = f2b(v.z); o.w = f2b(v.w);
  *(ushort4*)(out + i) = o;
}

// ---------------------------------------------------------------- transpose
__global__ __launch_bounds__(256) void transpose_f32_bf16(
    const float* __restrict__ in, unsigned short* __restrict__ out,
    int R, int C) {
  __shared__ float tile[32][33];
  const int tx = threadIdx.x & 31, ty = threadIdx.x >> 5;
  const int c0 = blockIdx.x * 32, r0 = blockIdx.y * 32;
#pragma unroll
  for (int i = 0; i < 32; i += 8)
    tile[ty + i][tx] = in[(size_t)(r0 + ty + i) * C + (c0 + tx)];
  __syncthreads();
#pragma unroll
  for (int i = 0; i < 32; i += 8)
    out[(size_t)(c0 + ty + i) * R + (r0 + tx)] = f2b(tile[tx][ty + i]);
}

// V [bh][t][d] -> Vt [bh][d][t], 64x64 bf16 tiles per block
__global__ __launch_bounds__(256) void vtrans(
    const unsigned short* __restrict__ in, unsigned short* __restrict__ out) {
  __shared__ __align__(16) unsigned short tile[64 * 72];
  const int tid = threadIdx.x;
  const int bh = blockIdx.y, t0 = blockIdx.x * 64;
  const unsigned short* src = in + (size_t)bh * 131072 + (size_t)t0 * 64;
  unsigned short* dst = out + (size_t)bh * 131072 + t0;
#pragma unroll
  for (int i = 0; i < 2; ++i) {
    const int c = tid + i * 256;           // 512 chunks of 8 elems
    u16x8 v = *(const u16x8*)(src + c * 8);
    *(u16x8*)&tile[(c >> 3) * 72 + (c & 7) * 8] = v;
  }
  __syncthreads();
#pragma unroll
  for (int i = 0; i < 2; ++i) {
    const int c = tid + i * 256;
    const int d = c >> 3, t8 = (c & 7) * 8;
    u16x8 o;
#pragma unroll
    for (int j = 0; j < 8; ++j) o[j] = tile[(t8 + j) * 72 + d];
    *(u16x8*)(dst + (size_t)d * 2048 + t8) = o;
  }
}

// ---------------------------------------------------------------- GEMM
// C[M,N] = A[M,K]*Bt[N,K]^T + bias. 128x128 tile, BK=32, 4 waves, m97-style
// global_load_lds staging.
// MODE 0: scatter bf16 to Q/K/V, all [b,h,t,d] (Q prescaled 0.125*log2e).
// MODE 1: fp32 row-major output (final projection).
#define QSCALE 0.18033688f  // 0.125 * log2(e)
template <int MODE>
__global__ __launch_bounds__(256, 2) void gemm_bt(
    const unsigned short* __restrict__ A, const unsigned short* __restrict__ Bt,
    const float* __restrict__ bias, void* __restrict__ out_v,
    int M, int N, int K) {
  __shared__ __align__(16) unsigned short As[128 * 32];
  __shared__ __align__(16) unsigned short Bs[128 * 32];
  const int tid = threadIdx.x;
  const int w = tid >> 6, l = tid & 63, g = l >> 4, ln = l & 15;
  const int m0 = blockIdx.y * 128, n0 = blockIdx.x * 128;
  const int wm = (w & 1) * 64, wn = (w >> 1) * 64;

  f32x4 acc[4][4];
#pragma unroll
  for (int i = 0; i < 4; ++i)
#pragma unroll
    for (int j = 0; j < 4; ++j) acc[i][j] = (f32x4){0.f, 0.f, 0.f, 0.f};

  const unsigned short* Ab = A + (size_t)m0 * K;
  const unsigned short* Bb = Bt + (size_t)n0 * K;
  const int c0 = tid, c1 = tid + 256;
  const int ar0 = c0 >> 2, ak0 = (c0 & 3) * 8;
  const int ar1 = c1 >> 2, ak1 = (c1 & 3) * 8;

  for (int k0 = 0; k0 < K; k0 += 32) {
    gl_lds16(Ab + (size_t)ar0 * K + k0 + ak0, &As[c0 * 8]);
    gl_lds16(Ab + (size_t)ar1 * K + k0 + ak1, &As[c1 * 8]);
    gl_lds16(Bb + (size_t)ar0 * K + k0 + ak0, &Bs[c0 * 8]);
    gl_lds16(Bb + (size_t)ar1 * K + k0 + ak1, &Bs[c1 * 8]);
    __syncthreads();
    bf16x8 af[4], bf[4];
#pragma unroll
    for (int mi = 0; mi < 4; ++mi)
      af[mi] = *(const bf16x8*)&As[(wm + mi * 16 + ln) * 32 + g * 8];
#pragma unroll
    for (int ni = 0; ni < 4; ++ni)
      bf[ni] = *(const bf16x8*)&Bs[(wn + ni * 16 + ln) * 32 + g * 8];
#pragma unroll
    for (int mi = 0; mi < 4; ++mi)
#pragma unroll
      for (int ni = 0; ni < 4; ++ni)
        acc[mi][ni] = mfma16(af[mi], bf[ni], acc[mi][ni]);
    __syncthreads();
  }

#pragma unroll
  for (int mi = 0; mi < 4; ++mi) {
#pragma unroll
    for (int ni = 0; ni < 4; ++ni) {
      const int row0 = m0 + wm + mi * 16 + 4 * g;
      const int col = n0 + wn + ni * 16 + ln;
      const float bv = bias[col];
#pragma unroll
      for (int r = 0; r < 4; ++r) {
        float v = acc[mi][ni][r] + bv;
        const int row = row0 + r;
        if (MODE == 0) {
          const int which = col >> 10;           // 0=Q 1=K 2=V
          const int h = (col >> 6) & 15;
          const int dd = col & 63;
          const int b = row >> 11, t = row & 2047;
          unsigned short* dst = (unsigned short*)out_v + (size_t)which * 8388608u;
          if (which == 0) v *= QSCALE;
          dst[(((size_t)(b * 16 + h)) * 2048 + t) * 64 + dd] = f2b(v);
        } else {
          ((float*)out_v)[(size_t)row * N + col] = v;
        }
      }
    }
  }
}

// ---------------------------------------------------------------- attention
// One block per (bh, 128-q tile); 4 waves, wave w owns q rows [32w, 32w+32).
// mfma 32x32x16. Q prescaled (log2 domain), no online max, deferred
// l-normalization.
// SWAPPED QK^T: S^T = mfma32(K_frag, Q_frag) -> C/D col=l&31 is q, rows are
// keys at crow(r,lh)=(r&3)+8*(r>>2)+4*lh. Each lane owns P[q=l32][32 keys/nb].
// PV A-frag (m=q=l&31, k=lh*8+j) built in-register:
//   pk_swap(cvtpk(pe0,pe1), cvtpk(pe4,pe5)) -> ap.word0 (keys hi*8+{0,1})
//                                              ap.word2 (keys hi*8+{4,5})
// (verified mapping: hi=0 lane keeps crow 0..3/8..11, partner lane's packed
// pairs fill the hi*8 offsets via the half-wave swap).
// 32x32x16 layouts: A m=l&31,k=(l>>5)*8+j; B n=l&31,k=(l>>5)*8+j;
// C/D col=l&31, row=(reg&3)+8*(reg>>2)+4*(l>>5)  [HW-verified m74/m101].
__global__ __launch_bounds__(256, 2) void attn(
    const unsigned short* __restrict__ Q, const unsigned short* __restrict__ K,
    const unsigned short* __restrict__ Vtg, unsigned short* __restrict__ Y) {
  __shared__ __align__(16) unsigned short Qs[128 * 72];
  __shared__ __align__(16) unsigned short Ks[64 * 72];     // [key][d]
  __shared__ __align__(16) unsigned short Vt[64 * 72];     // [d][key]

  const int tid = threadIdx.x;
  const int w = tid >> 6, l = tid & 63;
  const int l32 = l & 31, lh = l >> 5;       // half-wave select
  const int bh = blockIdx.y;
  const int q0 = blockIdx.x * 128;

  const unsigned short* Qb = Q + (size_t)bh * 131072;    // [t][d]
  const unsigned short* Kb = K + (size_t)bh * 131072;    // [t][d]
  const unsigned short* Vb = Vtg + (size_t)bh * 131072;  // [d][t]

  // stage Q: 128x64 bf16 -> stride-72 rows
#pragma unroll
  for (int i = 0; i < 4; ++i) {
    const int c = tid + i * 256;   // 1024 chunks
    u16x8 v = *(const u16x8*)(Qb + (size_t)q0 * 64 + c * 8);
    *(u16x8*)&Qs[(c >> 3) * 72 + (c & 7) * 8] = v;
  }
  __syncthreads();
  // hoist Q fragments (B-operand now; same (idx=l&31, k) mapping as A)
  bf16x8 aq[4];
#pragma unroll
  for (int kb = 0; kb < 4; ++kb)
    aq[kb] = *(const bf16x8*)&Qs[(w * 32 + l32) * 72 + kb * 16 + lh * 8];

  f32x16 o[2];
#pragma unroll
  for (int db = 0; db < 2; ++db)
#pragma unroll
    for (int r = 0; r < 16; ++r) o[db][r] = 0.f;
  float lsum = 0.f;  // running denominator for q = l32 (this lane's key half)

  for (int kt = 0; kt < 32; ++kt) {
    // stage K tile [key][d] and V tile [d][key] (V^T global)
#pragma unroll
    for (int i = 0; i < 2; ++i) {
      const int c = tid + i * 256;
      const int row = c >> 3, cc = (c & 7) * 8;
      u16x8 kv = *(const u16x8*)(Kb + (size_t)kt * 4096 + c * 8);
      u16x8 vv = *(const u16x8*)(Vb + (size_t)row * 2048 + kt * 64 + cc);
      *(u16x8*)&Ks[row * 72 + cc] = kv;
      *(u16x8*)&Vt[row * 72 + cc] = vv;
    }
    __syncthreads();

    // S^T = K Q^T : per wave 64k x 32q, two 32-key blocks (A=K, B=Q)
    f32x16 s[2];
#pragma unroll
    for (int nb = 0; nb < 2; ++nb) {
#pragma unroll
      for (int r = 0; r < 16; ++r) s[nb][r] = 0.f;
#pragma unroll
      for (int kb = 0; kb < 4; ++kb) {
        bf16x8 bk = *(const bf16x8*)&Ks[(nb * 32 + l32) * 72 + kb * 16 + lh * 8];
        s[nb] = mfma32(bk, aq[kb], s[nb]);
      }
    }

    // exp2 + in-register P->bf16 A-fragments (no LDS round-trip)
    bf16x8 ap[4];
#pragma unroll
    for (int nb = 0; nb < 2; ++nb) {
      float pe[16];
#pragma unroll
      for (int r = 0; r < 16; ++r) {
        pe[r] = exp2f(s[nb][r]);
        lsum += pe[r];
      }
      union { unsigned int wd[4]; bf16x8 v; } u0, u1;
      pk_swap(pe[0], pe[1], pe[4], pe[5], u0.wd[0], u0.wd[2]);
      pk_swap(pe[2], pe[3], pe[6], pe[7], u0.wd[1], u0.wd[3]);
      pk_swap(pe[8], pe[9], pe[12], pe[13], u1.wd[0], u1.wd[2]);
      pk_swap(pe[10], pe[11], pe[14], pe[15], u1.wd[1], u1.wd[3]);
      ap[2 * nb + 0] = u0.v;   // keys nb*32 + [0,16)
      ap[2 * nb + 1] = u1.v;   // keys nb*32 + [16,32)
    }

    // PV: A = P (in-register), B = V^T
#pragma unroll
    for (int db = 0; db < 2; ++db)
#pragma unroll
      for (int ks = 0; ks < 4; ++ks) {
        bf16x8 bv = *(const bf16x8*)&Vt[(db * 32 + l32) * 72 + ks * 16 + lh * 8];
        o[db] = mfma32(ap[ks], bv, o[db]);
      }
    __syncthreads();  // all waves done with Ks/Vt before next staging
  }

  // combine the two key-halves: lanes l and l+32 both hold q = l&31
  lsum += __shfl_xor(lsum, 32, 64);
  // redistribute 1/l to the output layout (row r lives at lane crow(r,lh))
  float iv[16];
#pragma unroll
  for (int r = 0; r < 16; ++r) {
    const int row = (r & 3) + 8 * (r >> 2) + 4 * lh;
    iv[r] = 1.f / __shfl(lsum, row, 64);
  }

  // epilogue: y[b, t, h*64 + d]
  const int b = bh >> 4, h = bh & 15;
#pragma unroll
  for (int db = 0; db < 2; ++db)
#pragma unroll
    for (int r = 0; r < 16; ++r) {
      const int row = (r & 3) + 8 * (r >> 2) + 4 * lh;
      const int t = q0 + w * 32 + row;
      Y[(size_t)(b * 2048 + t) * 1024 + h * 64 + db * 32 + l32] =
          f2b(o[db][r] * iv[r]);
    }
}

// ---------------------------------------------------------------- launch
extern "C" void kernel_launch(void* const* d_in, const int* in_sizes, int n_in,
                              void* d_out, int out_size, void* d_ws, size_t ws_size,
                              hipStream_t stream) {
  const float* x     = (const float*)d_in[0];
  const float* Wqkv  = (const float*)d_in[1];
  const float* bqkv  = (const float*)d_in[2];
  const float* Wproj = (const float*)d_in[3];
  const float* bproj = (const float*)d_in[4];
  float* out = (float*)d_out;
  unsigned short* ws = (unsigned short*)d_ws;

  unsigned short* xbf    = ws;
  unsigned short* Yw     = xbf;  // alias: x dead after gemm<0>
  unsigned short* WqkvT  = xbf + 8388608;
  unsigned short* WprojT = WqkvT + 3072 * 1024;
  unsigned short* Qw     = WprojT + 1024 * 1024;
  unsigned short* Kw     = Qw + 8388608;
  unsigned short* Vw     = Kw + 8388608;   // [b,h,t,d]
  unsigned short* Vtw    = Vw + 8388608;   // [b,h,d,t]

  f32_to_bf16<<<8192, 256, 0, stream>>>(x, xbf, 2097152);
  transpose_f32_bf16<<<dim3(96, 32), 256, 0, stream>>>(Wqkv, WqkvT, 1024, 3072);
  transpose_f32_bf16<<<dim3(32, 32), 256, 0, stream>>>(Wproj, WprojT, 1024, 1024);
  gemm_bt<0><<<dim3(24, 64), 256, 0, stream>>>(xbf, WqkvT, bqkv, Qw, 8192, 3072, 1024);
  vtrans<<<dim3(32, 64), 256, 0, stream>>>(Vw, Vtw);
  attn<<<dim3(16, 64), 256, 0, stream>>>(Qw, Kw, Vtw, Yw);
  gemm_bt<1><<<dim3(8, 64), 256, 0, stream>>>(Yw, WprojT, bproj, out, 8192, 1024, 1024);
}

// Round 2
// 291.466 us; speedup vs baseline: 1.1021x; 1.0432x over previous
//
#include <hip/hip_runtime.h>

// MHSA. Inputs fp32, output fp32. B=4, T=2048, D=1024, H=16, hd=64.
// R9: attn softmax VALU diet:
//  (a) exp2f -> __builtin_amdgcn_exp2f (raw v_exp_f32; OCML wrapper was
//      ~7 VALU insts/elem = ~450 cyc/kt of the 1410-cyc VALU budget);
//  (b) lsum via MFMA ones-trick: os = mfma32(ap[ks], ones, os) accumulates
//      row-sums of bf16 P on the 25%-idle MFMA pipe, killing the 32-deep
//      serial f32 add chain per kt AND the 80-shuffle epilogue butterfly.
//      os[r] lands in the same C/D layout (q = crow(r,lh)) as o[db][r].

typedef __attribute__((ext_vector_type(8))) short bf16x8;
typedef __attribute__((ext_vector_type(8))) unsigned short u16x8;
typedef __attribute__((ext_vector_type(4))) float f32x4;
typedef __attribute__((ext_vector_type(16))) float f32x16;

#define DEV static __device__ __forceinline__

DEV unsigned short f2b(float f) {  // RTNE f32 -> bf16
  union { float f; unsigned int i; } v; v.f = f;
  unsigned int x = v.i;
  return (unsigned short)((x + 0x7FFFu + ((x >> 16) & 1u)) >> 16);
}

DEV f32x4 mfma16(bf16x8 a, bf16x8 b, f32x4 c) {
  return __builtin_amdgcn_mfma_f32_16x16x32_bf16(a, b, c, 0, 0, 0);
}
DEV f32x16 mfma32(bf16x8 a, bf16x8 b, f32x16 c) {
  return __builtin_amdgcn_mfma_f32_32x32x16_bf16(a, b, c, 0, 0, 0);
}

DEV void gl_lds16(const unsigned short* g, unsigned short* l) {
  __builtin_amdgcn_global_load_lds(
      (const __attribute__((address_space(1))) unsigned int*)g,
      (__attribute__((address_space(3))) unsigned int*)l, 16, 0, 0);
}

// cvt two f32 pairs to packed bf16, then swap upper-half(a) <-> lower-half(b)
// across the wave. Yields two A-frag words (see layout notes in attn).
DEV void pk_swap(float a0, float a1, float b0, float b1,
                 unsigned int& w_lo, unsigned int& w_hi) {
  unsigned int a, b;
  asm("v_cvt_pk_bf16_f32 %0, %1, %2" : "=v"(a) : "v"(a0), "v"(a1));
  asm("v_cvt_pk_bf16_f32 %0, %1, %2" : "=v"(b) : "v"(b0), "v"(b1));
  asm("v_permlane32_swap_b32 %0, %1" : "+v"(a), "+v"(b));
  w_lo = a; w_hi = b;
}

// ---------------------------------------------------------------- convert
__global__ __launch_bounds__(256) void f32_to_bf16(
    const float* __restrict__ in, unsigned short* __restrict__ out, int n4) {
  const int i = (blockIdx.x * 256 + threadIdx.x) * 4;
  if (i >= n4 * 4) return;
  const float4 v = *(const float4*)(in + i);
  ushort4 o;
  o.x = f2b(v.x); o.y = f2b(v.y); o.z = f2b(v.z); o.w = f2b(v.w);
  *(ushort4*)(out + i) = o;
}

// ---------------------------------------------------------------- transpose
__global__ __launch_bounds__(256) void transpose_f32_bf16(
    const float* __restrict__ in, unsigned short* __restrict__ out,
    int R, int C) {
  __shared__ float tile[32][33];
  const int tx = threadIdx.x & 31, ty = threadIdx.x >> 5;
  const int c0 = blockIdx.x * 32, r0 = blockIdx.y * 32;
#pragma unroll
  for (int i = 0; i < 32; i += 8)
    tile[ty + i][tx] = in[(size_t)(r0 + ty + i) * C + (c0 + tx)];
  __syncthreads();
#pragma unroll
  for (int i = 0; i < 32; i += 8)
    out[(size_t)(c0 + ty + i) * R + (r0 + tx)] = f2b(tile[tx][ty + i]);
}

// V [bh][t][d] -> Vt [bh][d][t], 64x64 bf16 tiles per block
__global__ __launch_bounds__(256) void vtrans(
    const unsigned short* __restrict__ in, unsigned short* __restrict__ out) {
  __shared__ __align__(16) unsigned short tile[64 * 72];
  const int tid = threadIdx.x;
  const int bh = blockIdx.y, t0 = blockIdx.x * 64;
  const unsigned short* src = in + (size_t)bh * 131072 + (size_t)t0 * 64;
  unsigned short* dst = out + (size_t)bh * 131072 + t0;
#pragma unroll
  for (int i = 0; i < 2; ++i) {
    const int c = tid + i * 256;           // 512 chunks of 8 elems
    u16x8 v = *(const u16x8*)(src + c * 8);
    *(u16x8*)&tile[(c >> 3) * 72 + (c & 7) * 8] = v;
  }
  __syncthreads();
#pragma unroll
  for (int i = 0; i < 2; ++i) {
    const int c = tid + i * 256;
    const int d = c >> 3, t8 = (c & 7) * 8;
    u16x8 o;
#pragma unroll
    for (int j = 0; j < 8; ++j) o[j] = tile[(t8 + j) * 72 + d];
    *(u16x8*)(dst + (size_t)d * 2048 + t8) = o;
  }
}

// ---------------------------------------------------------------- GEMM
// C[M,N] = A[M,K]*Bt[N,K]^T + bias. 128x128 tile, BK=32, 4 waves, m97-style
// global_load_lds staging.
// MODE 0: scatter bf16 to Q/K/V, all [b,h,t,d] (Q prescaled 0.125*log2e).
// MODE 1: fp32 row-major output (final projection).
#define QSCALE 0.18033688f  // 0.125 * log2(e)
template <int MODE>
__global__ __launch_bounds__(256, 2) void gemm_bt(
    const unsigned short* __restrict__ A, const unsigned short* __restrict__ Bt,
    const float* __restrict__ bias, void* __restrict__ out_v,
    int M, int N, int K) {
  __shared__ __align__(16) unsigned short As[128 * 32];
  __shared__ __align__(16) unsigned short Bs[128 * 32];
  const int tid = threadIdx.x;
  const int w = tid >> 6, l = tid & 63, g = l >> 4, ln = l & 15;
  const int m0 = blockIdx.y * 128, n0 = blockIdx.x * 128;
  const int wm = (w & 1) * 64, wn = (w >> 1) * 64;

  f32x4 acc[4][4];
#pragma unroll
  for (int i = 0; i < 4; ++i)
#pragma unroll
    for (int j = 0; j < 4; ++j) acc[i][j] = (f32x4){0.f, 0.f, 0.f, 0.f};

  const unsigned short* Ab = A + (size_t)m0 * K;
  const unsigned short* Bb = Bt + (size_t)n0 * K;
  const int c0 = tid, c1 = tid + 256;
  const int ar0 = c0 >> 2, ak0 = (c0 & 3) * 8;
  const int ar1 = c1 >> 2, ak1 = (c1 & 3) * 8;

  for (int k0 = 0; k0 < K; k0 += 32) {
    gl_lds16(Ab + (size_t)ar0 * K + k0 + ak0, &As[c0 * 8]);
    gl_lds16(Ab + (size_t)ar1 * K + k0 + ak1, &As[c1 * 8]);
    gl_lds16(Bb + (size_t)ar0 * K + k0 + ak0, &Bs[c0 * 8]);
    gl_lds16(Bb + (size_t)ar1 * K + k0 + ak1, &Bs[c1 * 8]);
    __syncthreads();
    bf16x8 af[4], bf[4];
#pragma unroll
    for (int mi = 0; mi < 4; ++mi)
      af[mi] = *(const bf16x8*)&As[(wm + mi * 16 + ln) * 32 + g * 8];
#pragma unroll
    for (int ni = 0; ni < 4; ++ni)
      bf[ni] = *(const bf16x8*)&Bs[(wn + ni * 16 + ln) * 32 + g * 8];
#pragma unroll
    for (int mi = 0; mi < 4; ++mi)
#pragma unroll
      for (int ni = 0; ni < 4; ++ni)
        acc[mi][ni] = mfma16(af[mi], bf[ni], acc[mi][ni]);
    __syncthreads();
  }

#pragma unroll
  for (int mi = 0; mi < 4; ++mi) {
#pragma unroll
    for (int ni = 0; ni < 4; ++ni) {
      const int row0 = m0 + wm + mi * 16 + 4 * g;
      const int col = n0 + wn + ni * 16 + ln;
      const float bv = bias[col];
#pragma unroll
      for (int r = 0; r < 4; ++r) {
        float v = acc[mi][ni][r] + bv;
        const int row = row0 + r;
        if (MODE == 0) {
          const int which = col >> 10;           // 0=Q 1=K 2=V
          const int h = (col >> 6) & 15;
          const int dd = col & 63;
          const int b = row >> 11, t = row & 2047;
          unsigned short* dst = (unsigned short*)out_v + (size_t)which * 8388608u;
          if (which == 0) v *= QSCALE;
          dst[(((size_t)(b * 16 + h)) * 2048 + t) * 64 + dd] = f2b(v);
        } else {
          ((float*)out_v)[(size_t)row * N + col] = v;
        }
      }
    }
  }
}

// ---------------------------------------------------------------- attention
// One block per (bh, 128-q tile); 4 waves, wave w owns q rows [32w, 32w+32).
// mfma 32x32x16. Q prescaled (log2 domain), no online max, deferred
// l-normalization.
// SWAPPED QK^T: S^T = mfma32(K_frag, Q_frag) -> C/D col=l&31 is q, rows are
// keys at crow(r,lh)=(r&3)+8*(r>>2)+4*lh. Each lane owns P[q=l32][32 keys/nb].
// PV A-frag (m=q=l&31, k=lh*8+j) built in-register via pk_swap.
// Row-sums: os = mfma32(ap[ks], ones, os) -> os[r] = lsum(q=crow(r,lh)),
// identical layout to o[db][r]; epilogue needs no shuffles.
// 32x32x16 layouts: A m=l&31,k=(l>>5)*8+j; B n=l&31,k=(l>>5)*8+j;
// C/D col=l&31, row=(reg&3)+8*(reg>>2)+4*(l>>5)  [HW-verified m74/m101].
__global__ __launch_bounds__(256, 2) void attn(
    const unsigned short* __restrict__ Q, const unsigned short* __restrict__ K,
    const unsigned short* __restrict__ Vtg, unsigned short* __restrict__ Y) {
  __shared__ __align__(16) unsigned short Qs[128 * 72];
  __shared__ __align__(16) unsigned short Ks[64 * 72];     // [key][d]
  __shared__ __align__(16) unsigned short Vt[64 * 72];     // [d][key]

  const int tid = threadIdx.x;
  const int w = tid >> 6, l = tid & 63;
  const int l32 = l & 31, lh = l >> 5;       // half-wave select
  const int bh = blockIdx.y;
  const int q0 = blockIdx.x * 128;

  const unsigned short* Qb = Q + (size_t)bh * 131072;    // [t][d]
  const unsigned short* Kb = K + (size_t)bh * 131072;    // [t][d]
  const unsigned short* Vb = Vtg + (size_t)bh * 131072;  // [d][t]

  // stage Q: 128x64 bf16 -> stride-72 rows
#pragma unroll
  for (int i = 0; i < 4; ++i) {
    const int c = tid + i * 256;   // 1024 chunks
    u16x8 v = *(const u16x8*)(Qb + (size_t)q0 * 64 + c * 8);
    *(u16x8*)&Qs[(c >> 3) * 72 + (c & 7) * 8] = v;
  }
  __syncthreads();
  // hoist Q fragments (B-operand now; same (idx=l&31, k) mapping as A)
  bf16x8 aq[4];
#pragma unroll
  for (int kb = 0; kb < 4; ++kb)
    aq[kb] = *(const bf16x8*)&Qs[(w * 32 + l32) * 72 + kb * 16 + lh * 8];

  // ones B-frag (bf16 1.0 = 0x3F80) for the row-sum MFMA
  const short one_b = (short)0x3F80;
  const bf16x8 vones = (bf16x8){one_b, one_b, one_b, one_b,
                                one_b, one_b, one_b, one_b};

  f32x16 o[2], os;
#pragma unroll
  for (int db = 0; db < 2; ++db)
#pragma unroll
    for (int r = 0; r < 16; ++r) o[db][r] = 0.f;
#pragma unroll
  for (int r = 0; r < 16; ++r) os[r] = 0.f;

  for (int kt = 0; kt < 32; ++kt) {
    // stage K tile [key][d] and V tile [d][key] (V^T global)
#pragma unroll
    for (int i = 0; i < 2; ++i) {
      const int c = tid + i * 256;
      const int row = c >> 3, cc = (c & 7) * 8;
      u16x8 kv = *(const u16x8*)(Kb + (size_t)kt * 4096 + c * 8);
      u16x8 vv = *(const u16x8*)(Vb + (size_t)row * 2048 + kt * 64 + cc);
      *(u16x8*)&Ks[row * 72 + cc] = kv;
      *(u16x8*)&Vt[row * 72 + cc] = vv;
    }
    __syncthreads();

    // S^T = K Q^T : per wave 64k x 32q, two 32-key blocks (A=K, B=Q)
    f32x16 s[2];
#pragma unroll
    for (int nb = 0; nb < 2; ++nb) {
#pragma unroll
      for (int r = 0; r < 16; ++r) s[nb][r] = 0.f;
#pragma unroll
      for (int kb = 0; kb < 4; ++kb) {
        bf16x8 bk = *(const bf16x8*)&Ks[(nb * 32 + l32) * 72 + kb * 16 + lh * 8];
        s[nb] = mfma32(bk, aq[kb], s[nb]);
      }
    }

    // raw v_exp_f32 + in-register P->bf16 A-fragments (no LDS round-trip)
    bf16x8 ap[4];
#pragma unroll
    for (int nb = 0; nb < 2; ++nb) {
      float pe[16];
#pragma unroll
      for (int r = 0; r < 16; ++r)
        pe[r] = __builtin_amdgcn_exp2f(s[nb][r]);
      union { unsigned int wd[4]; bf16x8 v; } u0, u1;
      pk_swap(pe[0], pe[1], pe[4], pe[5], u0.wd[0], u0.wd[2]);
      pk_swap(pe[2], pe[3], pe[6], pe[7], u0.wd[1], u0.wd[3]);
      pk_swap(pe[8], pe[9], pe[12], pe[13], u1.wd[0], u1.wd[2]);
      pk_swap(pe[10], pe[11], pe[14], pe[15], u1.wd[1], u1.wd[3]);
      ap[2 * nb + 0] = u0.v;   // keys nb*32 + [0,16)
      ap[2 * nb + 1] = u1.v;   // keys nb*32 + [16,32)
    }

    // PV: A = P (in-register), B = V^T; row-sum on the MFMA pipe
#pragma unroll
    for (int ks = 0; ks < 4; ++ks) {
      os = mfma32(ap[ks], vones, os);
#pragma unroll
      for (int db = 0; db < 2; ++db) {
        bf16x8 bv = *(const bf16x8*)&Vt[(db * 32 + l32) * 72 + ks * 16 + lh * 8];
        o[db] = mfma32(ap[ks], bv, o[db]);
      }
    }
    __syncthreads();  // all waves done with Ks/Vt before next staging
  }

  // os[r] = sum over all keys of P[q=crow(r,lh)] -- same layout as o[db][r]
  float iv[16];
#pragma unroll
  for (int r = 0; r < 16; ++r) iv[r] = 1.f / os[r];

  // epilogue: y[b, t, h*64 + d]
  const int b = bh >> 4, h = bh & 15;
#pragma unroll
  for (int db = 0; db < 2; ++db)
#pragma unroll
    for (int r = 0; r < 16; ++r) {
      const int row = (r & 3) + 8 * (r >> 2) + 4 * lh;
      const int t = q0 + w * 32 + row;
      Y[(size_t)(b * 2048 + t) * 1024 + h * 64 + db * 32 + l32] =
          f2b(o[db][r] * iv[r]);
    }
}

// ---------------------------------------------------------------- launch
extern "C" void kernel_launch(void* const* d_in, const int* in_sizes, int n_in,
                              void* d_out, int out_size, void* d_ws, size_t ws_size,
                              hipStream_t stream) {
  const float* x     = (const float*)d_in[0];
  const float* Wqkv  = (const float*)d_in[1];
  const float* bqkv  = (const float*)d_in[2];
  const float* Wproj = (const float*)d_in[3];
  const float* bproj = (const float*)d_in[4];
  float* out = (float*)d_out;
  unsigned short* ws = (unsigned short*)d_ws;

  unsigned short* xbf    = ws;
  unsigned short* Yw     = xbf;  // alias: x dead after gemm<0>
  unsigned short* WqkvT  = xbf + 8388608;
  unsigned short* WprojT = WqkvT + 3072 * 1024;
  unsigned short* Qw     = WprojT + 1024 * 1024;
  unsigned short* Kw     = Qw + 8388608;
  unsigned short* Vw     = Kw + 8388608;   // [b,h,t,d]
  unsigned short* Vtw    = Vw + 8388608;   // [b,h,d,t]

  f32_to_bf16<<<8192, 256, 0, stream>>>(x, xbf, 2097152);
  transpose_f32_bf16<<<dim3(96, 32), 256, 0, stream>>>(Wqkv, WqkvT, 1024, 3072);
  transpose_f32_bf16<<<dim3(32, 32), 256, 0, stream>>>(Wproj, WprojT, 1024, 1024);
  gemm_bt<0><<<dim3(24, 64), 256, 0, stream>>>(xbf, WqkvT, bqkv, Qw, 8192, 3072, 1024);
  vtrans<<<dim3(32, 64), 256, 0, stream>>>(Vw, Vtw);
  attn<<<dim3(16, 64), 256, 0, stream>>>(Qw, Kw, Vtw, Yw);
  gemm_bt<1><<<dim3(8, 64), 256, 0, stream>>>(Yw, WprojT, bproj, out, 8192, 1024, 1024);
}